// Round 5
// baseline (163.076 us; speedup 1.0000x reference)
//
#include <hip/hip_runtime.h>
#include <hip/hip_bf16.h>

#define N_NODES 8192
#define E_EDGES 16384
#define S_SEG   16
#define EXT     64
#define P_PATHS 2048
#define ROW     1024            // S_SEG*EXT floats per row
#define L_SLOTS 4               // edge slots per wave
#define NWAVES  (E_EDGES / L_SLOTS)   // 4096
#define NBLK    (NWAVES / 4)          // 1024 blocks x 4 waves

typedef _Float16 f16x8  __attribute__((ext_vector_type(8)));
typedef _Float16 f16x4  __attribute__((ext_vector_type(4)));
typedef _Float16 half2v __attribute__((ext_vector_type(2)));
typedef float    f32x4  __attribute__((ext_vector_type(4)));

// ---- workspace layout (bytes) ----
#define WS_CMAT  0        // f16[4096]   8 KB
#define WS_HIST  8192     // int[8192]
#define WS_CURS  40960    // int[8192]
#define WS_ROWS  73728    // int[8193]
#define WS_ELIST 106512   // int[16384]
#define WS_XRS   172048   // int[16384]  gather row per sorted slot
#define WS_NDS   237584   // int[16384]  output node per sorted slot

// ---------------------------------------------------------------------------
__global__ void prep(const int* __restrict__ pidx, const float* __restrict__ pcoef,
                     _Float16* __restrict__ Cmat, int* __restrict__ hist) {
    const int tid = threadIdx.x;
    if (blockIdx.x < 32) { hist[blockIdx.x * 256 + tid] = 0; return; }
    __shared__ float sC[S_SEG * S_SEG * S_SEG];
    for (int i = tid; i < 4096; i += 256) sC[i] = 0.f;
    __syncthreads();
    for (int p = tid; p < P_PATHS; p += 256) {
        int i = pidx[3 * p + 0];
        int j = pidx[3 * p + 1];
        int k = pidx[3 * p + 2];
        atomicAdd(&sC[(k * S_SEG + i) * S_SEG + j], pcoef[p]);
    }
    __syncthreads();
    for (int i = tid; i < 4096; i += 256) Cmat[i] = (_Float16)sC[i];
}

__global__ void hist_k(const int* __restrict__ idx_out, int* __restrict__ hist) {
    const int e = blockIdx.x * 256 + threadIdx.x;
    atomicAdd(&hist[idx_out[e]], 1);
}

__global__ __launch_bounds__(256) void scan_k(const int* __restrict__ hist,
                                              int* __restrict__ rows,
                                              int* __restrict__ cursor) {
    __shared__ int part[256];
    const int t = threadIdx.x;
    const int base = t * 32;
    int loc[32];
    int s = 0;
#pragma unroll
    for (int i = 0; i < 32; ++i) { loc[i] = s; s += hist[base + i]; }
    part[t] = s;
    __syncthreads();
    for (int off = 1; off < 256; off <<= 1) {
        int v = part[t];
        int u = (t >= off) ? part[t - off] : 0;
        __syncthreads();
        part[t] = v + u;
        __syncthreads();
    }
    const int excl = (t == 0) ? 0 : part[t - 1];
#pragma unroll
    for (int i = 0; i < 32; ++i) {
        int v = excl + loc[i];
        rows[base + i] = v;
        cursor[base + i] = v;
    }
    if (t == 255) rows[N_NODES] = part[255];
}

__global__ void scatter_k(const int* __restrict__ idx_in, const int* __restrict__ idx_out,
                          int* __restrict__ cursor, int* __restrict__ elist,
                          int* __restrict__ xrs, int* __restrict__ nds) {
    const int e = blockIdx.x * 256 + threadIdx.x;
    const int nd = idx_out[e];
    const int pos = atomicAdd(&cursor[nd], 1);
    elist[pos] = e;
    xrs[pos]   = idx_in[e];
    nds[pos]   = nd;
}

// zero the tiles of deg-0 nodes and nodes whose slot range crosses a wave boundary
__global__ __launch_bounds__(256) void zerofill_k(const int* __restrict__ rows,
                                                  float* __restrict__ out) {
    const int n = blockIdx.x * 4 + (threadIdx.x >> 6);
    const int lane = threadIdx.x & 63;
    const int beg = rows[n], end = rows[n + 1];
    const bool need = (beg == end) || ((beg / L_SLOTS) != ((end - 1) / L_SLOTS));
    if (!need) return;
    const f32x4 z = {0.f, 0.f, 0.f, 0.f};
    float* ob = out + (size_t)n * ROW + lane * 4;
#pragma unroll
    for (int r = 0; r < 4; ++r)
        __builtin_nontemporal_store(z, (f32x4*)(ob + r * 256));
}

// ---------------------------------------------------------------------------
// main: one wave per L_SLOTS consecutive sorted edge slots; register
// double-buffer prefetch of next edge's x/y rows; fp16 MFMA; plain store for
// fully-owned nodes, atomicAdd onto zeroed background for boundary nodes.
// ---------------------------------------------------------------------------
__global__ __launch_bounds__(256) void seg_poly_slots(
        const float* __restrict__ x, const float* __restrict__ y,
        const _Float16* __restrict__ Cmat,
        const int* __restrict__ elist, const int* __restrict__ xrs,
        const int* __restrict__ nds, float* __restrict__ out) {
    __shared__ __attribute__((aligned(16))) _Float16 sx_all[4][ROW];
    __shared__ __attribute__((aligned(16))) half2v   sy_all[4][512];

    const int tid  = threadIdx.x;
    const int lane = tid & 63;
    const int wv   = tid >> 6;
    _Float16* sxh = sx_all[wv];
    half2v*   syp = sy_all[wv];

    const int wid = blockIdx.x * 4 + wv;     // 0..4095
    const int s0  = wid * L_SLOTS;

    const int quad = lane >> 4;
    const int m    = lane & 15;
    const int jb2  = (quad & 1) * 4;
    const int ih   = quad >> 1;
    const int jp   = lane >> 3;          // 0..7
    const int cq   = (lane & 7) * 8;     // 8 cols per lane

    // per-slot metadata (wave-uniform)
    int e_[L_SLOTS], xr_[L_SLOTS], nd_[L_SLOTS];
    {
        int4 a = *(const int4*)(elist + s0);
        e_[0]=a.x; e_[1]=a.y; e_[2]=a.z; e_[3]=a.w;
        a = *(const int4*)(xrs + s0);
        xr_[0]=a.x; xr_[1]=a.y; xr_[2]=a.z; xr_[3]=a.w;
        a = *(const int4*)(nds + s0);
        nd_[0]=a.x; nd_[1]=a.y; nd_[2]=a.z; nd_[3]=a.w;
    }
    const bool prev_same = (s0 > 0)                  && (nds[s0 - 1]       == nd_[0]);
    const bool next_same = (s0 + L_SLOTS < E_EDGES)  && (nds[s0 + L_SLOTS] == nd_[L_SLOTS - 1]);

    // A fragments (constant): afrag[kk][jr] = Cmat[m][kk*32 + quad*8 + jr]
    f16x8 afrag[8];
    {
        const _Float16* basep = Cmat + m * 256 + quad * 8;
#pragma unroll
        for (int kk = 0; kk < 8; ++kk) afrag[kk] = *(const f16x8*)(basep + kk * 32);
    }

    f32x4 xbuf[2][4], ybuf[2][4];
    auto issue = [&](int t, int b) {
        const float* xp = x + (size_t)xr_[t] * ROW;
        const float* yp = y + (size_t)e_[t] * ROW;
#pragma unroll
        for (int k4 = 0; k4 < 4; ++k4)
            xbuf[b][k4] = *(const f32x4*)(xp + k4 * 256 + lane * 4);
        // y is read exactly once ever -> non-temporal, keep L2/L3 for x gather
        ybuf[b][0] = __builtin_nontemporal_load((const f32x4*)(yp + (2 * jp)     * EXT + cq));
        ybuf[b][1] = __builtin_nontemporal_load((const f32x4*)(yp + (2 * jp)     * EXT + cq + 4));
        ybuf[b][2] = __builtin_nontemporal_load((const f32x4*)(yp + (2 * jp + 1) * EXT + cq));
        ybuf[b][3] = __builtin_nontemporal_load((const f32x4*)(yp + (2 * jp + 1) * EXT + cq + 4));
    };
    issue(0, 0);

    f32x4 acc[4];
#pragma unroll
    for (int ct = 0; ct < 4; ++ct) acc[ct] = f32x4{0.f, 0.f, 0.f, 0.f};
    int segStart = 0;

#pragma unroll
    for (int t = 0; t < L_SLOTS; ++t) {
        const int b = t & 1;
        if (t + 1 < L_SLOTS) issue(t + 1, b ^ 1);   // prefetch next edge

        // stage current edge regs -> f16 LDS (wave-private, no barriers)
#pragma unroll
        for (int k4 = 0; k4 < 4; ++k4) {
            const f32x4 v = xbuf[b][k4];
            *(f16x4*)(sxh + k4 * 256 + lane * 4) =
                f16x4{(_Float16)v[0], (_Float16)v[1], (_Float16)v[2], (_Float16)v[3]};
        }
        {
            const f32x4 a0 = ybuf[b][0], a1 = ybuf[b][1];
            const f32x4 c0 = ybuf[b][2], c1 = ybuf[b][3];
            *(f16x8*)(syp + jp * 64 + cq) =
                f16x8{(_Float16)a0[0], (_Float16)c0[0], (_Float16)a0[1], (_Float16)c0[1],
                      (_Float16)a0[2], (_Float16)c0[2], (_Float16)a0[3], (_Float16)c0[3]};
            *(f16x8*)(syp + jp * 64 + cq + 4) =
                f16x8{(_Float16)a1[0], (_Float16)c1[0], (_Float16)a1[1], (_Float16)c1[1],
                      (_Float16)a1[2], (_Float16)c1[2], (_Float16)a1[3], (_Float16)c1[3]};
        }

        // compute: 4 col-tiles x 8 K-steps of mfma_f32_16x16x32_f16
#pragma unroll
        for (int ct = 0; ct < 4; ++ct) {
            const int c = ct * 16 + m;
            half2v ypk[4];
#pragma unroll
            for (int r = 0; r < 4; ++r) ypk[r] = syp[(jb2 + r) * 64 + c];
#pragma unroll
            for (int kk = 0; kk < 8; ++kk) {
                const _Float16 xh = sxh[(2 * kk + ih) * EXT + c];
                const half2v hx = {xh, xh};
                const half2v b0 = hx * ypk[0];
                const half2v b1 = hx * ypk[1];
                const half2v b2 = hx * ypk[2];
                const half2v b3 = hx * ypk[3];
                const f16x8 bfrag = {b0[0], b0[1], b1[0], b1[1],
                                     b2[0], b2[1], b3[0], b3[1]};
                acc[ct] = __builtin_amdgcn_mfma_f32_16x16x32_f16(
                              afrag[kk], bfrag, acc[ct], 0, 0, 0);
            }
        }

        // flush at node boundary
        const bool last = (t == L_SLOTS - 1);
        if (last || nd_[t + 1] != nd_[t]) {
            const bool shared = (segStart == 0 && prev_same) || (last && next_same);
            float* ob = out + (size_t)nd_[t] * ROW;
            if (shared) {
#pragma unroll
                for (int ct = 0; ct < 4; ++ct)
#pragma unroll
                    for (int r = 0; r < 4; ++r)
                        atomicAdd(ob + (quad * 4 + r) * EXT + ct * 16 + m, acc[ct][r]);
            } else {
#pragma unroll
                for (int ct = 0; ct < 4; ++ct)
#pragma unroll
                    for (int r = 0; r < 4; ++r)
                        __builtin_nontemporal_store(
                            acc[ct][r], ob + (quad * 4 + r) * EXT + ct * 16 + m);
            }
#pragma unroll
            for (int ct = 0; ct < 4; ++ct) acc[ct] = f32x4{0.f, 0.f, 0.f, 0.f};
            segStart = t + 1;
        }
    }
}

extern "C" void kernel_launch(void* const* d_in, const int* in_sizes, int n_in,
                              void* d_out, int out_size, void* d_ws, size_t ws_size,
                              hipStream_t stream) {
    const float* x       = (const float*)d_in[0];
    const float* y       = (const float*)d_in[1];
    const int*   idx_in  = (const int*)d_in[2];
    const int*   idx_out = (const int*)d_in[3];
    const int*   pidx    = (const int*)d_in[4];
    const float* pcoef   = (const float*)d_in[5];
    float* out           = (float*)d_out;

    char* ws = (char*)d_ws;
    _Float16* Cmat = (_Float16*)(ws + WS_CMAT);
    int* hist      = (int*)(ws + WS_HIST);
    int* cursor    = (int*)(ws + WS_CURS);
    int* rows      = (int*)(ws + WS_ROWS);
    int* elist     = (int*)(ws + WS_ELIST);
    int* xrs       = (int*)(ws + WS_XRS);
    int* nds       = (int*)(ws + WS_NDS);

    prep<<<33, 256, 0, stream>>>(pidx, pcoef, Cmat, hist);
    hist_k<<<E_EDGES / 256, 256, 0, stream>>>(idx_out, hist);
    scan_k<<<1, 256, 0, stream>>>(hist, rows, cursor);
    scatter_k<<<E_EDGES / 256, 256, 0, stream>>>(idx_in, idx_out, cursor, elist, xrs, nds);
    zerofill_k<<<N_NODES / 4, 256, 0, stream>>>(rows, out);
    seg_poly_slots<<<NBLK, 256, 0, stream>>>(x, y, Cmat, elist, xrs, nds, out);
}